// Round 10
// baseline (164.052 us; speedup 1.0000x reference)
//
#include <hip/hip_runtime.h>
#include <stdint.h>

typedef unsigned long long u64;

#define NPTS 32768
#define NCEN 512
#define DIM  128
#define TOPK 10

#define BM 128
#define BN 128
#define KSTEP 32
#define LDT 132      // padded LDS row width (floats): conflict-free b128 reads
#define KP 21        // keysL row stride (u64) per point: 20 used + 1 pad

// LDS: GEMM phase xT+cT = 2*32*132*4 = 33792 B ; keys phase 128*21*8 = 21504 B (aliased)
#define SMEM1 33792

// ---------------- numpy pairwise_sum(v*v) over n=128, bit-exact; cen + x in one launch ----
// numpy (n <= PW_BLOCKSIZE=128): 8 chains r_j = sum_b fl(a[8b+j]^2), b ascending,
// then ((r0+r1)+(r2+r3))+((r4+r5)+(r6+r7)). Products rounded separately (no FMA).
__global__ __launch_bounds__(256) void np_rownorm_all(const float* __restrict__ x,
                                                      const float* __restrict__ cen,
                                                      float* __restrict__ x2,
                                                      float* __restrict__ c2) {
  const int t = threadIdx.x;
  const int lane = t & 63;
  const int wv = t >> 6;
  const int g = lane >> 3;      // row within wave (0..7)
  const int j = lane & 7;       // chain index (0..7)
  const int row = blockIdx.x * 32 + wv * 8 + g;   // 0..33279 (512 cen + 32768 x)
  if (row >= NCEN + NPTS) return;
  const float* p;
  float* dst;
  if (row < NCEN) { p = cen + (size_t)row * DIM; dst = c2 + row; }
  else            { p = x + (size_t)(row - NCEN) * DIM; dst = x2 + (row - NCEN); }

  float v = p[j];
  float r = __fmul_rn(v, v);
#pragma unroll
  for (int b = 1; b < 16; ++b) {
    v = p[8 * b + j];
    r = __fadd_rn(r, __fmul_rn(v, v));
  }
  r = __fadd_rn(r, __shfl_xor(r, 1, 64));
  r = __fadd_rn(r, __shfl_xor(r, 2, 64));
  r = __fadd_rn(r, __shfl_xor(r, 4, 64));
  if (j == 0) *dst = r;
}

// ---------------- GEMM (numpy-exact) + per-wave top-10 selection ----------------
// 256 thr / 4 waves (2x2 of 64x64), KSTEP=32, 33.8KB LDS.
// REGISTER-BUDGET MODEL (rounds 3-9 evidence): hipcc targets occupancy from
// LDS-allowed blocks/CU. 33.8KB -> 4 blocks/CU -> 4 waves/EU target -> 128
// unified regs/wave -> 64 arch VGPR + acc[8][8] bounced through AGPRs (VGPR=64,
// 110us, 3x FMA floor). Round 3's 135KB LDS -> 1 wave/EU -> 512 budget -> clean
// VGPR=132 loop. Fix: pin waves_per_eu(2,2) -> 256-reg budget, acc stays in
// arch VGPRs, runtime occupancy from usage (~3 waves/EU).
__global__ __launch_bounds__(256)
__attribute__((amdgpu_waves_per_eu(2, 2)))
void gemm_select_kernel(const float* __restrict__ x,
                        const float* __restrict__ cen,
                        const float* __restrict__ x2,
                        const float* __restrict__ c2,
                        u64* __restrict__ keysG) {
  __shared__ __align__(16) char smem[SMEM1];
  float* xT = (float*)smem;                    // [KSTEP][LDT]
  float* cT = (float*)(smem + 16896);          // [KSTEP][LDT]
  u64*  keysL = (u64*)smem;                    // [128][KP]  (aliased after barrier)

  const int t  = threadIdx.x;
  const int pb = blockIdx.y * BM;
  const int cb = blockIdx.x * BN;

  const int srow = t & 127;
  const int kh   = (t >> 7) * 16;

  const int wid  = t >> 6;
  const int lane = t & 63;
  const int wr = wid >> 1, wc = wid & 1;
  const int r = lane & 7, c = lane >> 3;
  const int px = wr * 64 + 4 * r;
  const int cx = wc * 64 + 4 * c;

  float acc[8][8];
#pragma unroll
  for (int i = 0; i < 8; ++i)
#pragma unroll
    for (int j = 0; j < 8; ++j) acc[i][j] = 0.f;

  for (int s = 0; s < DIM / KSTEP; ++s) {
    if (s) __syncthreads();
    {
      const float4* srcx = (const float4*)&x[(size_t)(pb + srow) * DIM + s * KSTEP + kh];
      const float4* srcc = (const float4*)&cen[(size_t)(cb + srow) * DIM + s * KSTEP + kh];
#pragma unroll
      for (int i = 0; i < 4; ++i) {
        float4 v = srcx[i];
        int k = kh + i * 4;
        xT[(k + 0) * LDT + srow] = v.x; xT[(k + 1) * LDT + srow] = v.y;
        xT[(k + 2) * LDT + srow] = v.z; xT[(k + 3) * LDT + srow] = v.w;
      }
#pragma unroll
      for (int i = 0; i < 4; ++i) {
        float4 v = srcc[i];
        int k = kh + i * 4;
        cT[(k + 0) * LDT + srow] = v.x; cT[(k + 1) * LDT + srow] = v.y;
        cT[(k + 2) * LDT + srow] = v.z; cT[(k + 3) * LDT + srow] = v.w;
      }
    }
    __syncthreads();

#pragma unroll 4
    for (int kk = 0; kk < KSTEP; ++kk) {
      float4 xa  = *(const float4*)&xT[kk * LDT + px];
      float4 xb  = *(const float4*)&xT[kk * LDT + px + 32];
      float4 ca  = *(const float4*)&cT[kk * LDT + cx];
      float4 cb2 = *(const float4*)&cT[kk * LDT + cx + 32];
      float xv[8] = {xa.x, xa.y, xa.z, xa.w, xb.x, xb.y, xb.z, xb.w};
      float cv[8] = {ca.x, ca.y, ca.z, ca.w, cb2.x, cb2.y, cb2.z, cb2.w};
#pragma unroll
      for (int i = 0; i < 8; ++i)
#pragma unroll
        for (int j = 0; j < 8; ++j)
          acc[i][j] = __fmaf_rn(xv[i], cv[j], acc[i][j]);
    }
  }
  __syncthreads();   // all waves done reading xT/cT before keysL aliases them

  // ---- per-wave selection: sorted top-10 of this wave's 64-center slice, per point ----
  const float4 cc0 = *(const float4*)&c2[cb + cx];
  const float4 cc1 = *(const float4*)&c2[cb + cx + 32];
#pragma unroll
  for (int i = 0; i < 8; ++i) {
    const int pt = px + (i & 3) + (i >> 2) * 32;
    const float xx = x2[pb + pt];
    u64 key[8];
#pragma unroll
    for (int jq = 0; jq < 2; ++jq) {
      const float4 cc = jq ? cc1 : cc0;
      float t0 = __fmaf_rn(-2.f, acc[i][jq * 4 + 0], xx);
      float t1 = __fmaf_rn(-2.f, acc[i][jq * 4 + 1], xx);
      float t2 = __fmaf_rn(-2.f, acc[i][jq * 4 + 2], xx);
      float t3 = __fmaf_rn(-2.f, acc[i][jq * 4 + 3], xx);
      float d0 = sqrtf(fmaxf(__fadd_rn(t0, cc.x), 0.f));
      float d1 = sqrtf(fmaxf(__fadd_rn(t1, cc.y), 0.f));
      float d2 = sqrtf(fmaxf(__fadd_rn(t2, cc.z), 0.f));
      float d3 = sqrtf(fmaxf(__fadd_rn(t3, cc.w), 0.f));
      const unsigned cbase = (unsigned)(cb + cx + 32 * jq);
      key[jq * 4 + 0] = ((u64)__float_as_uint(d0) << 32) | (cbase + 0);
      key[jq * 4 + 1] = ((u64)__float_as_uint(d1) << 32) | (cbase + 1);
      key[jq * 4 + 2] = ((u64)__float_as_uint(d2) << 32) | (cbase + 2);
      key[jq * 4 + 3] = ((u64)__float_as_uint(d3) << 32) | (cbase + 3);
    }
#pragma unroll
    for (int tt = 0; tt < TOPK; ++tt) {
      u64 m = key[0];
#pragma unroll
      for (int s2 = 1; s2 < 8; ++s2) m = (key[s2] < m) ? key[s2] : m;
      u64 o;
      o = __shfl_xor(m, 8, 64);  m = (o < m) ? o : m;
      o = __shfl_xor(m, 16, 64); m = (o < m) ? o : m;
      o = __shfl_xor(m, 32, 64); m = (o < m) ? o : m;
      if (c == 0) keysL[pt * KP + wc * 10 + tt] = m;
#pragma unroll
      for (int s2 = 0; s2 < 8; ++s2)
        if (key[s2] == m) key[s2] = ~0ull;
    }
  }
  __syncthreads();

  // ---- coalesced dump: 20 u64/point -> keysG[(pb+p)*80 + (cb>>6)*10 + q] ----
  {
    const int p = t >> 1, half = t & 1;
    const u64* srcL = &keysL[p * KP + half * 10];
    u64* dst = &keysG[(size_t)(pb + p) * 80 + (cb >> 6) * 10 + half * 10];
#pragma unroll
    for (int q = 0; q < 10; ++q) dst[q] = srcL[q];
  }
}

// ---------------- merge 8 sorted 10-lists per point + gather ----------------
// one wave per point; keys read 640B contiguous; tournament via per-lane-src shuffles.
__global__ __launch_bounds__(256) void merge_gather_kernel(const u64* __restrict__ keysG,
                                                           const float* __restrict__ x,
                                                           float* __restrict__ out) {
  const int p    = blockIdx.x * 4 + (threadIdx.x >> 6);
  const int lane = threadIdx.x & 63;

  const u64* kp = keysG + (size_t)p * 80;
  u64 ka = kp[lane];
  u64 kb = (lane < 16) ? kp[64 + lane] : ~0ull;

  float* op = out + (size_t)p * TOPK * DIM;
  int ptr = 0;   // list-head pointer for lane < 8 (list id = lane)

#pragma unroll
  for (int tt = 0; tt < TOPK; ++tt) {
    const int src = lane * 10 + ptr;
    u64 ha = __shfl(ka, src, 64);
    u64 hb = __shfl(kb, (src >= 64) ? (src - 64) : 0, 64);
    u64 head = (lane < 8 && ptr < 10) ? ((src < 64) ? ha : hb) : ~0ull;
    u64 m = head, o;
    o = __shfl_xor(m, 1, 64); m = (o < m) ? o : m;
    o = __shfl_xor(m, 2, 64); m = (o < m) ? o : m;
    o = __shfl_xor(m, 4, 64); m = (o < m) ? o : m;
    m = __shfl(m, 0, 64);                 // broadcast winner to all 64 lanes
    if (head == m) ptr++;                 // unique keys -> exactly one winner lane
    const int idx = (int)(m & 0x1ffull);  // cluster index in [0,512)
    const float2 v = *(const float2*)&x[(size_t)idx * DIM + 2 * lane];
    *(float2*)&op[tt * DIM + 2 * lane] = v;
  }
}

extern "C" void kernel_launch(void* const* d_in, const int* in_sizes, int n_in,
                              void* d_out, int out_size, void* d_ws, size_t ws_size,
                              hipStream_t stream) {
  const float* x   = (const float*)d_in[0];
  const float* cen = (const float*)d_in[1];
  float* out = (float*)d_out;

  // ws layout: [c2: 2KB pad->4KB][x2: 128KB][keys: 21MB]
  float* c2 = (float*)d_ws;
  float* x2 = (float*)((char*)d_ws + 4096);
  u64* keys = (u64*)((char*)d_ws + 4096 + 131072);

  np_rownorm_all<<<(NCEN + NPTS) / 32, 256, 0, stream>>>(x, cen, x2, c2);
  gemm_select_kernel<<<dim3(NCEN / BN, NPTS / BM), 256, 0, stream>>>(x, cen, x2, c2, keys);
  merge_gather_kernel<<<NPTS / 4, 256, 0, stream>>>(keys, x, out);
}

// Round 11
// 159.710 us; speedup vs baseline: 1.0272x; 1.0272x over previous
//
#include <hip/hip_runtime.h>
#include <stdint.h>

typedef unsigned long long u64;

#define NPTS 32768
#define NCEN 512
#define DIM  128
#define TOPK 10

#define BM 128
#define BN 128
#define KSTEP 32
#define LDT 132      // padded LDS row width (floats): conflict-free b128 reads
#define KP 21        // keysL row stride (u64) per point: 20 used + 1 pad

// LDS: GEMM phase xT+cT = 2*32*132*4 = 33792 B ; keys phase 128*21*8 = 21504 B (aliased)
#define SMEM1 33792

// Pin 8 floats into ARCH VGPRs (constraint "v"): zero-instruction inline asm.
// gfx950 VALU cannot mix AGPR+VGPR operands, so AGPR-resident accumulators pay
// v_accvgpr_read/write around every FMA (rounds 4-10: VGPR_Count 60-88, 2.6x
// VALU cycles). "+v" forces the register class the attributes couldn't.
#define PIN8(a) asm("" : "+v"(a[0]), "+v"(a[1]), "+v"(a[2]), "+v"(a[3]), \
                         "+v"(a[4]), "+v"(a[5]), "+v"(a[6]), "+v"(a[7]))
#define PIN_ACC(acc) do { PIN8(acc[0]); PIN8(acc[1]); PIN8(acc[2]); PIN8(acc[3]); \
                          PIN8(acc[4]); PIN8(acc[5]); PIN8(acc[6]); PIN8(acc[7]); } while (0)

// ---------------- numpy pairwise_sum(v*v) over n=128, bit-exact; cen + x in one launch ----
// numpy (n <= PW_BLOCKSIZE=128): 8 chains r_j = sum_b fl(a[8b+j]^2), b ascending,
// then ((r0+r1)+(r2+r3))+((r4+r5)+(r6+r7)). Products rounded separately (no FMA).
__global__ __launch_bounds__(256) void np_rownorm_all(const float* __restrict__ x,
                                                      const float* __restrict__ cen,
                                                      float* __restrict__ x2,
                                                      float* __restrict__ c2) {
  const int t = threadIdx.x;
  const int lane = t & 63;
  const int wv = t >> 6;
  const int g = lane >> 3;      // row within wave (0..7)
  const int j = lane & 7;       // chain index (0..7)
  const int row = blockIdx.x * 32 + wv * 8 + g;   // 0..33279 (512 cen + 32768 x)
  if (row >= NCEN + NPTS) return;
  const float* p;
  float* dst;
  if (row < NCEN) { p = cen + (size_t)row * DIM; dst = c2 + row; }
  else            { p = x + (size_t)(row - NCEN) * DIM; dst = x2 + (row - NCEN); }

  float v = p[j];
  float r = __fmul_rn(v, v);
#pragma unroll
  for (int b = 1; b < 16; ++b) {
    v = p[8 * b + j];
    r = __fadd_rn(r, __fmul_rn(v, v));
  }
  r = __fadd_rn(r, __shfl_xor(r, 1, 64));
  r = __fadd_rn(r, __shfl_xor(r, 2, 64));
  r = __fadd_rn(r, __shfl_xor(r, 4, 64));
  if (j == 0) *dst = r;
}

// ---------------- GEMM (numpy-exact) + per-wave top-10 selection ----------------
// 256 thr / 4 waves (2x2 of 64x64), KSTEP=32, 33.8KB LDS.
// waves_per_eu(3,3): unified budget 512/3 = 170 regs -> room for ~130 arch VGPRs
// without scratch; PIN_ACC forces acc[8][8] into arch VGPRs (see PIN8 comment).
__global__ __launch_bounds__(256)
__attribute__((amdgpu_waves_per_eu(3, 3)))
void gemm_select_kernel(const float* __restrict__ x,
                        const float* __restrict__ cen,
                        const float* __restrict__ x2,
                        const float* __restrict__ c2,
                        u64* __restrict__ keysG) {
  __shared__ __align__(16) char smem[SMEM1];
  float* xT = (float*)smem;                    // [KSTEP][LDT]
  float* cT = (float*)(smem + 16896);          // [KSTEP][LDT]
  u64*  keysL = (u64*)smem;                    // [128][KP]  (aliased after barrier)

  const int t  = threadIdx.x;
  const int pb = blockIdx.y * BM;
  const int cb = blockIdx.x * BN;

  const int srow = t & 127;
  const int kh   = (t >> 7) * 16;

  const int wid  = t >> 6;
  const int lane = t & 63;
  const int wr = wid >> 1, wc = wid & 1;
  const int r = lane & 7, c = lane >> 3;
  const int px = wr * 64 + 4 * r;
  const int cx = wc * 64 + 4 * c;

  float acc[8][8];
#pragma unroll
  for (int i = 0; i < 8; ++i)
#pragma unroll
    for (int j = 0; j < 8; ++j) acc[i][j] = 0.f;

  for (int s = 0; s < DIM / KSTEP; ++s) {
    if (s) __syncthreads();
    {
      const float4* srcx = (const float4*)&x[(size_t)(pb + srow) * DIM + s * KSTEP + kh];
      const float4* srcc = (const float4*)&cen[(size_t)(cb + srow) * DIM + s * KSTEP + kh];
#pragma unroll
      for (int i = 0; i < 4; ++i) {
        float4 v = srcx[i];
        int k = kh + i * 4;
        xT[(k + 0) * LDT + srow] = v.x; xT[(k + 1) * LDT + srow] = v.y;
        xT[(k + 2) * LDT + srow] = v.z; xT[(k + 3) * LDT + srow] = v.w;
      }
#pragma unroll
      for (int i = 0; i < 4; ++i) {
        float4 v = srcc[i];
        int k = kh + i * 4;
        cT[(k + 0) * LDT + srow] = v.x; cT[(k + 1) * LDT + srow] = v.y;
        cT[(k + 2) * LDT + srow] = v.z; cT[(k + 3) * LDT + srow] = v.w;
      }
    }
    __syncthreads();

    PIN_ACC(acc);   // acc must be in arch VGPRs entering the FMA loop
#pragma unroll 4
    for (int kk = 0; kk < KSTEP; ++kk) {
      float4 xa  = *(const float4*)&xT[kk * LDT + px];
      float4 xb  = *(const float4*)&xT[kk * LDT + px + 32];
      float4 ca  = *(const float4*)&cT[kk * LDT + cx];
      float4 cb2 = *(const float4*)&cT[kk * LDT + cx + 32];
      float xv[8] = {xa.x, xa.y, xa.z, xa.w, xb.x, xb.y, xb.z, xb.w};
      float cv[8] = {ca.x, ca.y, ca.z, ca.w, cb2.x, cb2.y, cb2.z, cb2.w};
#pragma unroll
      for (int i = 0; i < 8; ++i)
#pragma unroll
        for (int j = 0; j < 8; ++j)
          acc[i][j] = __fmaf_rn(xv[i], cv[j], acc[i][j]);
    }
    PIN_ACC(acc);   // ...and leaving it
  }
  __syncthreads();   // all waves done reading xT/cT before keysL aliases them

  // ---- per-wave selection: sorted top-10 of this wave's 64-center slice, per point ----
  const float4 cc0 = *(const float4*)&c2[cb + cx];
  const float4 cc1 = *(const float4*)&c2[cb + cx + 32];
#pragma unroll
  for (int i = 0; i < 8; ++i) {
    const int pt = px + (i & 3) + (i >> 2) * 32;
    const float xx = x2[pb + pt];
    u64 key[8];
#pragma unroll
    for (int jq = 0; jq < 2; ++jq) {
      const float4 cc = jq ? cc1 : cc0;
      float t0 = __fmaf_rn(-2.f, acc[i][jq * 4 + 0], xx);
      float t1 = __fmaf_rn(-2.f, acc[i][jq * 4 + 1], xx);
      float t2 = __fmaf_rn(-2.f, acc[i][jq * 4 + 2], xx);
      float t3 = __fmaf_rn(-2.f, acc[i][jq * 4 + 3], xx);
      float d0 = sqrtf(fmaxf(__fadd_rn(t0, cc.x), 0.f));
      float d1 = sqrtf(fmaxf(__fadd_rn(t1, cc.y), 0.f));
      float d2 = sqrtf(fmaxf(__fadd_rn(t2, cc.z), 0.f));
      float d3 = sqrtf(fmaxf(__fadd_rn(t3, cc.w), 0.f));
      const unsigned cbase = (unsigned)(cb + cx + 32 * jq);
      key[jq * 4 + 0] = ((u64)__float_as_uint(d0) << 32) | (cbase + 0);
      key[jq * 4 + 1] = ((u64)__float_as_uint(d1) << 32) | (cbase + 1);
      key[jq * 4 + 2] = ((u64)__float_as_uint(d2) << 32) | (cbase + 2);
      key[jq * 4 + 3] = ((u64)__float_as_uint(d3) << 32) | (cbase + 3);
    }
#pragma unroll
    for (int tt = 0; tt < TOPK; ++tt) {
      u64 m = key[0];
#pragma unroll
      for (int s2 = 1; s2 < 8; ++s2) m = (key[s2] < m) ? key[s2] : m;
      u64 o;
      o = __shfl_xor(m, 8, 64);  m = (o < m) ? o : m;
      o = __shfl_xor(m, 16, 64); m = (o < m) ? o : m;
      o = __shfl_xor(m, 32, 64); m = (o < m) ? o : m;
      if (c == 0) keysL[pt * KP + wc * 10 + tt] = m;
#pragma unroll
      for (int s2 = 0; s2 < 8; ++s2)
        if (key[s2] == m) key[s2] = ~0ull;
    }
  }
  __syncthreads();

  // ---- coalesced dump: 20 u64/point -> keysG[(pb+p)*80 + (cb>>6)*10 + q] ----
  {
    const int p = t >> 1, half = t & 1;
    const u64* srcL = &keysL[p * KP + half * 10];
    u64* dst = &keysG[(size_t)(pb + p) * 80 + (cb >> 6) * 10 + half * 10];
#pragma unroll
    for (int q = 0; q < 10; ++q) dst[q] = srcL[q];
  }
}

// ---------------- merge 8 sorted 10-lists per point + gather ----------------
// one wave per point; keys read 640B contiguous; tournament via per-lane-src shuffles.
__global__ __launch_bounds__(256) void merge_gather_kernel(const u64* __restrict__ keysG,
                                                           const float* __restrict__ x,
                                                           float* __restrict__ out) {
  const int p    = blockIdx.x * 4 + (threadIdx.x >> 6);
  const int lane = threadIdx.x & 63;

  const u64* kp = keysG + (size_t)p * 80;
  u64 ka = kp[lane];
  u64 kb = (lane < 16) ? kp[64 + lane] : ~0ull;

  float* op = out + (size_t)p * TOPK * DIM;
  int ptr = 0;   // list-head pointer for lane < 8 (list id = lane)

#pragma unroll
  for (int tt = 0; tt < TOPK; ++tt) {
    const int src = lane * 10 + ptr;
    u64 ha = __shfl(ka, src, 64);
    u64 hb = __shfl(kb, (src >= 64) ? (src - 64) : 0, 64);
    u64 head = (lane < 8 && ptr < 10) ? ((src < 64) ? ha : hb) : ~0ull;
    u64 m = head, o;
    o = __shfl_xor(m, 1, 64); m = (o < m) ? o : m;
    o = __shfl_xor(m, 2, 64); m = (o < m) ? o : m;
    o = __shfl_xor(m, 4, 64); m = (o < m) ? o : m;
    m = __shfl(m, 0, 64);                 // broadcast winner to all 64 lanes
    if (head == m) ptr++;                 // unique keys -> exactly one winner lane
    const int idx = (int)(m & 0x1ffull);  // cluster index in [0,512)
    const float2 v = *(const float2*)&x[(size_t)idx * DIM + 2 * lane];
    *(float2*)&op[tt * DIM + 2 * lane] = v;
  }
}

extern "C" void kernel_launch(void* const* d_in, const int* in_sizes, int n_in,
                              void* d_out, int out_size, void* d_ws, size_t ws_size,
                              hipStream_t stream) {
  const float* x   = (const float*)d_in[0];
  const float* cen = (const float*)d_in[1];
  float* out = (float*)d_out;

  // ws layout: [c2: 2KB pad->4KB][x2: 128KB][keys: 21MB]
  float* c2 = (float*)d_ws;
  float* x2 = (float*)((char*)d_ws + 4096);
  u64* keys = (u64*)((char*)d_ws + 4096 + 131072);

  np_rownorm_all<<<(NCEN + NPTS) / 32, 256, 0, stream>>>(x, cen, x2, c2);
  gemm_select_kernel<<<dim3(NCEN / BN, NPTS / BM), 256, 0, stream>>>(x, cen, x2, c2, keys);
  merge_gather_kernel<<<NPTS / 4, 256, 0, stream>>>(keys, x, out);
}

// Round 12
// 146.354 us; speedup vs baseline: 1.1209x; 1.0913x over previous
//
#include <hip/hip_runtime.h>
#include <stdint.h>

typedef unsigned long long u64;

#define NPTS 32768
#define NCEN 512
#define DIM  128
#define TOPK 10

#define BM 128
#define BN 128
#define KSTEP 32
#define LDT 132      // padded LDS row width (floats): conflict-free b128 reads
#define KP 21        // keysL row stride (u64) per point: 20 used + 1 pad

// LDS: GEMM phase xT+cT = 2*32*132*4 = 33792 B ; keys phase 128*21*8 = 21504 B (aliased)
#define SMEM1 33792

// ---------------- numpy pairwise_sum(v*v) over n=128, bit-exact; cen + x in one launch ----
// numpy (n <= PW_BLOCKSIZE=128): 8 chains r_j = sum_b fl(a[8b+j]^2), b ascending,
// then ((r0+r1)+(r2+r3))+((r4+r5)+(r6+r7)). Products rounded separately (no FMA).
__global__ __launch_bounds__(256) void np_rownorm_all(const float* __restrict__ x,
                                                      const float* __restrict__ cen,
                                                      float* __restrict__ x2,
                                                      float* __restrict__ c2) {
  const int t = threadIdx.x;
  const int lane = t & 63;
  const int wv = t >> 6;
  const int g = lane >> 3;      // row within wave (0..7)
  const int j = lane & 7;       // chain index (0..7)
  const int row = blockIdx.x * 32 + wv * 8 + g;   // 0..33279 (512 cen + 32768 x)
  if (row >= NCEN + NPTS) return;
  const float* p;
  float* dst;
  if (row < NCEN) { p = cen + (size_t)row * DIM; dst = c2 + row; }
  else            { p = x + (size_t)(row - NCEN) * DIM; dst = x2 + (row - NCEN); }

  float v = p[j];
  float r = __fmul_rn(v, v);
#pragma unroll
  for (int b = 1; b < 16; ++b) {
    v = p[8 * b + j];
    r = __fadd_rn(r, __fmul_rn(v, v));
  }
  r = __fadd_rn(r, __shfl_xor(r, 1, 64));
  r = __fadd_rn(r, __shfl_xor(r, 2, 64));
  r = __fadd_rn(r, __shfl_xor(r, 4, 64));
  if (j == 0) *dst = r;
}

// ---------------- GEMM (numpy-exact) + per-wave top-10 selection ----------------
// 256 thr / 4 waves (2x2 of 64x64), KSTEP=32, 33.8KB LDS.
// ROUNDS 4-11: every attribute-based attempt left acc[8][8] outside arch VGPRs
// (VGPR_Count 60-88, in-loop accvgpr/spill moves, VALU-busy 2.6x the FMA floor).
// FIX: the 64 FMAs are inline asm with "v"-constrained tied operands -- arch-VGPR
// residency is forced by construction. v_fmac_f32 == __fmaf_rn (IEEE fused, RNE);
// per-acc k-chain stays sequential ascending (numpy/BLAS order).
#define FMA_ROW(ai, xs)                                                         \
  asm("v_fmac_f32 %0, %8, %9\n\t"                                               \
      "v_fmac_f32 %1, %8, %10\n\t"                                              \
      "v_fmac_f32 %2, %8, %11\n\t"                                              \
      "v_fmac_f32 %3, %8, %12\n\t"                                              \
      "v_fmac_f32 %4, %8, %13\n\t"                                              \
      "v_fmac_f32 %5, %8, %14\n\t"                                              \
      "v_fmac_f32 %6, %8, %15\n\t"                                              \
      "v_fmac_f32 %7, %8, %16"                                                  \
      : "+v"(acc[ai][0]), "+v"(acc[ai][1]), "+v"(acc[ai][2]), "+v"(acc[ai][3]), \
        "+v"(acc[ai][4]), "+v"(acc[ai][5]), "+v"(acc[ai][6]), "+v"(acc[ai][7])  \
      : "v"(xs), "v"(ca.x), "v"(ca.y), "v"(ca.z), "v"(ca.w),                    \
        "v"(cb2.x), "v"(cb2.y), "v"(cb2.z), "v"(cb2.w))

__global__ __launch_bounds__(256)
__attribute__((amdgpu_waves_per_eu(1, 4)))
void gemm_select_kernel(const float* __restrict__ x,
                        const float* __restrict__ cen,
                        const float* __restrict__ x2,
                        const float* __restrict__ c2,
                        u64* __restrict__ keysG) {
  __shared__ __align__(16) char smem[SMEM1];
  float* xT = (float*)smem;                    // [KSTEP][LDT]
  float* cT = (float*)(smem + 16896);          // [KSTEP][LDT]
  u64*  keysL = (u64*)smem;                    // [128][KP]  (aliased after barrier)

  const int t  = threadIdx.x;
  const int pb = blockIdx.y * BM;
  const int cb = blockIdx.x * BN;

  const int srow = t & 127;
  const int kh   = (t >> 7) * 16;

  const int wid  = t >> 6;
  const int lane = t & 63;
  const int wr = wid >> 1, wc = wid & 1;
  const int r = lane & 7, c = lane >> 3;
  const int px = wr * 64 + 4 * r;
  const int cx = wc * 64 + 4 * c;

  float acc[8][8];
#pragma unroll
  for (int i = 0; i < 8; ++i)
#pragma unroll
    for (int j = 0; j < 8; ++j) acc[i][j] = 0.f;

  for (int s = 0; s < DIM / KSTEP; ++s) {
    if (s) __syncthreads();
    {
      const float4* srcx = (const float4*)&x[(size_t)(pb + srow) * DIM + s * KSTEP + kh];
      const float4* srcc = (const float4*)&cen[(size_t)(cb + srow) * DIM + s * KSTEP + kh];
#pragma unroll
      for (int i = 0; i < 4; ++i) {
        float4 v = srcx[i];
        int k = kh + i * 4;
        xT[(k + 0) * LDT + srow] = v.x; xT[(k + 1) * LDT + srow] = v.y;
        xT[(k + 2) * LDT + srow] = v.z; xT[(k + 3) * LDT + srow] = v.w;
      }
#pragma unroll
      for (int i = 0; i < 4; ++i) {
        float4 v = srcc[i];
        int k = kh + i * 4;
        cT[(k + 0) * LDT + srow] = v.x; cT[(k + 1) * LDT + srow] = v.y;
        cT[(k + 2) * LDT + srow] = v.z; cT[(k + 3) * LDT + srow] = v.w;
      }
    }
    __syncthreads();

#pragma unroll 4
    for (int kk = 0; kk < KSTEP; ++kk) {
      float4 xa  = *(const float4*)&xT[kk * LDT + px];
      float4 xb  = *(const float4*)&xT[kk * LDT + px + 32];
      float4 ca  = *(const float4*)&cT[kk * LDT + cx];
      float4 cb2 = *(const float4*)&cT[kk * LDT + cx + 32];
      FMA_ROW(0, xa.x);
      FMA_ROW(1, xa.y);
      FMA_ROW(2, xa.z);
      FMA_ROW(3, xa.w);
      FMA_ROW(4, xb.x);
      FMA_ROW(5, xb.y);
      FMA_ROW(6, xb.z);
      FMA_ROW(7, xb.w);
    }
  }
  __syncthreads();   // all waves done reading xT/cT before keysL aliases them

  // ---- per-wave selection: sorted top-10 of this wave's 64-center slice, per point ----
  const float4 cc0 = *(const float4*)&c2[cb + cx];
  const float4 cc1 = *(const float4*)&c2[cb + cx + 32];
#pragma unroll
  for (int i = 0; i < 8; ++i) {
    const int pt = px + (i & 3) + (i >> 2) * 32;
    const float xx = x2[pb + pt];
    u64 key[8];
#pragma unroll
    for (int jq = 0; jq < 2; ++jq) {
      const float4 cc = jq ? cc1 : cc0;
      float t0 = __fmaf_rn(-2.f, acc[i][jq * 4 + 0], xx);
      float t1 = __fmaf_rn(-2.f, acc[i][jq * 4 + 1], xx);
      float t2 = __fmaf_rn(-2.f, acc[i][jq * 4 + 2], xx);
      float t3 = __fmaf_rn(-2.f, acc[i][jq * 4 + 3], xx);
      float d0 = sqrtf(fmaxf(__fadd_rn(t0, cc.x), 0.f));
      float d1 = sqrtf(fmaxf(__fadd_rn(t1, cc.y), 0.f));
      float d2 = sqrtf(fmaxf(__fadd_rn(t2, cc.z), 0.f));
      float d3 = sqrtf(fmaxf(__fadd_rn(t3, cc.w), 0.f));
      const unsigned cbase = (unsigned)(cb + cx + 32 * jq);
      key[jq * 4 + 0] = ((u64)__float_as_uint(d0) << 32) | (cbase + 0);
      key[jq * 4 + 1] = ((u64)__float_as_uint(d1) << 32) | (cbase + 1);
      key[jq * 4 + 2] = ((u64)__float_as_uint(d2) << 32) | (cbase + 2);
      key[jq * 4 + 3] = ((u64)__float_as_uint(d3) << 32) | (cbase + 3);
    }
#pragma unroll
    for (int tt = 0; tt < TOPK; ++tt) {
      u64 m = key[0];
#pragma unroll
      for (int s2 = 1; s2 < 8; ++s2) m = (key[s2] < m) ? key[s2] : m;
      u64 o;
      o = __shfl_xor(m, 8, 64);  m = (o < m) ? o : m;
      o = __shfl_xor(m, 16, 64); m = (o < m) ? o : m;
      o = __shfl_xor(m, 32, 64); m = (o < m) ? o : m;
      if (c == 0) keysL[pt * KP + wc * 10 + tt] = m;
#pragma unroll
      for (int s2 = 0; s2 < 8; ++s2)
        if (key[s2] == m) key[s2] = ~0ull;
    }
  }
  __syncthreads();

  // ---- coalesced dump: 20 u64/point -> keysG[(pb+p)*80 + (cb>>6)*10 + q] ----
  {
    const int p = t >> 1, half = t & 1;
    const u64* srcL = &keysL[p * KP + half * 10];
    u64* dst = &keysG[(size_t)(pb + p) * 80 + (cb >> 6) * 10 + half * 10];
#pragma unroll
    for (int q = 0; q < 10; ++q) dst[q] = srcL[q];
  }
}

// ---------------- merge 8 sorted 10-lists per point + gather ----------------
// one wave per point; keys read 640B contiguous; tournament via per-lane-src shuffles.
__global__ __launch_bounds__(256) void merge_gather_kernel(const u64* __restrict__ keysG,
                                                           const float* __restrict__ x,
                                                           float* __restrict__ out) {
  const int p    = blockIdx.x * 4 + (threadIdx.x >> 6);
  const int lane = threadIdx.x & 63;

  const u64* kp = keysG + (size_t)p * 80;
  u64 ka = kp[lane];
  u64 kb = (lane < 16) ? kp[64 + lane] : ~0ull;

  float* op = out + (size_t)p * TOPK * DIM;
  int ptr = 0;   // list-head pointer for lane < 8 (list id = lane)

#pragma unroll
  for (int tt = 0; tt < TOPK; ++tt) {
    const int src = lane * 10 + ptr;
    u64 ha = __shfl(ka, src, 64);
    u64 hb = __shfl(kb, (src >= 64) ? (src - 64) : 0, 64);
    u64 head = (lane < 8 && ptr < 10) ? ((src < 64) ? ha : hb) : ~0ull;
    u64 m = head, o;
    o = __shfl_xor(m, 1, 64); m = (o < m) ? o : m;
    o = __shfl_xor(m, 2, 64); m = (o < m) ? o : m;
    o = __shfl_xor(m, 4, 64); m = (o < m) ? o : m;
    m = __shfl(m, 0, 64);                 // broadcast winner to all 64 lanes
    if (head == m) ptr++;                 // unique keys -> exactly one winner lane
    const int idx = (int)(m & 0x1ffull);  // cluster index in [0,512)
    const float2 v = *(const float2*)&x[(size_t)idx * DIM + 2 * lane];
    *(float2*)&op[tt * DIM + 2 * lane] = v;
  }
}

extern "C" void kernel_launch(void* const* d_in, const int* in_sizes, int n_in,
                              void* d_out, int out_size, void* d_ws, size_t ws_size,
                              hipStream_t stream) {
  const float* x   = (const float*)d_in[0];
  const float* cen = (const float*)d_in[1];
  float* out = (float*)d_out;

  // ws layout: [c2: 2KB pad->4KB][x2: 128KB][keys: 21MB]
  float* c2 = (float*)d_ws;
  float* x2 = (float*)((char*)d_ws + 4096);
  u64* keys = (u64*)((char*)d_ws + 4096 + 131072);

  np_rownorm_all<<<(NCEN + NPTS) / 32, 256, 0, stream>>>(x, cen, x2, c2);
  gemm_select_kernel<<<dim3(NCEN / BN, NPTS / BM), 256, 0, stream>>>(x, cen, x2, c2, keys);
  merge_gather_kernel<<<NPTS / 4, 256, 0, stream>>>(keys, x, out);
}